// Round 21
// baseline (61.667 us; speedup 1.0000x reference)
//
#include <hip/hip_runtime.h>
#include <stdint.h>

#define SEQ 512
#define BATCH 8
#define HID 1024

typedef __attribute__((ext_vector_type(8))) __bf16 bf16x8;
typedef __attribute__((ext_vector_type(4))) float f32x4;
typedef __attribute__((ext_vector_type(2))) float f32x2;

__device__ __forceinline__ unsigned short f2bf(float f) {
    unsigned int u = __float_as_uint(f);
    unsigned int r = 0x7fffu + ((u >> 16) & 1u);
    return (unsigned short)((u + r) >> 16);
}

__device__ __forceinline__ f32x2 up2(unsigned int v) {
    f32x2 r;
    r.x = __uint_as_float(v << 16);
    r.y = __uint_as_float(v & 0xffff0000u);
    return r;
}

template <int CTRL>
__device__ __forceinline__ float dpp_add(float x) {
    int t = __builtin_amdgcn_update_dpp(0, __float_as_int(x), CTRL, 0xf, 0xf, true);
    return x + __int_as_float(t);
}
__device__ __forceinline__ float wave_sum63(float x) {
    x = dpp_add<0x111>(x);
    x = dpp_add<0x112>(x);
    x = dpp_add<0x114>(x);
    x = dpp_add<0x118>(x);
    x = dpp_add<0x142>(x);
    x = dpp_add<0x143>(x);
    return x;
}

// ---- 1. prep: cast + transpose only (identical to R20) ----
__global__ __launch_bounds__(256) void k_prep(const float* __restrict__ seq,
                                              const float* __restrict__ W1,
                                              ushort* __restrict__ seqb,
                                              ushort* __restrict__ Bt) {
    __shared__ float tile[32][33];
    const int bid = blockIdx.x;
    const int tid = threadIdx.x;
    if (bid < 4096) {
        int i = bid * 256 + tid;  // < 1048576 = n4
        float4 v = ((const float4*)seq)[i];
        ushort4 o;
        o.x = f2bf(v.x); o.y = f2bf(v.y); o.z = f2bf(v.z); o.w = f2bf(v.w);
        ((ushort4*)seqb)[i] = o;
    } else {
        int idx = bid - 4096;
        int nb = (idx & 63) * 32, kb = (idx >> 6) * 32;
        int tx = tid & 31, ty = tid >> 5;
        int n = nb + tx;
        int rb = (n < 1024) ? 0 : 1024;
        int nc = n - rb;
#pragma unroll
        for (int i = 0; i < 4; ++i) {
            int k = kb + ty + i * 8;
            tile[ty + i * 8][tx] = W1[(size_t)(rb + k) * 1024 + nc];
        }
        __syncthreads();
#pragma unroll
        for (int i = 0; i < 4; ++i) {
            int n2 = nb + ty + i * 8;
            Bt[(size_t)n2 * 1024 + kb + tx] = f2bf(tile[tx][ty + i * 8]);
        }
    }
}

// ---- 2. 8-phase-style GEMM: 256x128 tile, 8 waves (4Mx2N of 64x64), BK=64,
//         3-deep LDS pipeline (144KB dynamic), 4 phases/K-tile, vmcnt(6)/tile.
//         blocks [0,256): GEMM | [256,286): width table | [286,292): W2t ----
__global__ __launch_bounds__(512) void k_gemm2(const ushort* __restrict__ A,
                                               const ushort* __restrict__ Bt,
                                               const float* __restrict__ wemb,
                                               const float* __restrict__ W1,
                                               const float* __restrict__ b1,
                                               const float* __restrict__ W2,
                                               ushort* __restrict__ P,
                                               ushort* __restrict__ Q,
                                               float* __restrict__ Rf,
                                               float* __restrict__ W2t) {
    extern __shared__ ushort sm[];  // 3 x (A 16384 + B 8192) = 73728 ushorts = 144 KB
    const int tid = threadIdx.x;
    const int bid = blockIdx.x;
    if (bid >= 256) {
        if (bid < 286) {
            int idx = (bid - 256) * 512 + tid;  // < 15360
            int w = idx >> 10, j = idx & 1023;
            float a0 = b1[j], a1 = 0.f, a2 = 0.f, a3 = 0.f;
#pragma unroll
            for (int c = 0; c < 64; c += 4) {
                a0 = fmaf(wemb[w * 64 + c + 0], W1[(size_t)(2048 + c + 0) * 1024 + j], a0);
                a1 = fmaf(wemb[w * 64 + c + 1], W1[(size_t)(2048 + c + 1) * 1024 + j], a1);
                a2 = fmaf(wemb[w * 64 + c + 2], W1[(size_t)(2048 + c + 2) * 1024 + j], a2);
                a3 = fmaf(wemb[w * 64 + c + 3], W1[(size_t)(2048 + c + 3) * 1024 + j], a3);
            }
            Rf[idx] = (a0 + a1) + (a2 + a3);
        } else {
            int idx = (bid - 286) * 512 + tid;  // < 3072
            int l = idx >> 10, j = idx & 1023;
            W2t[idx] = W2[j * 3 + l];
        }
        return;
    }
    const int wid = tid >> 6;     // 0..7
    const int lane = tid & 63;
    // bijective XCD swizzle: 256 blocks = 8 XCD x (4 m-tiles x 8 n-tiles)
    const int x = bid & 7, tt = bid >> 3;
    const int mt = ((x >> 1) << 2) + (tt >> 3);   // 0..15
    const int nt = ((x & 1) << 3) + (tt & 7);     // 0..15
    const int m0 = mt * 256;
    const int n0 = nt * 128;
    const int wm = (wid >> 1) * 64;   // 0,64,128,192
    const int wn = (wid & 1) * 64;    // 0,64
    const int srow = lane >> 2;
    const int scol = (lane & 3) * 8;
    const int fr = lane & 15;
    const int fk = (lane >> 4) * 8;

    f32x4 acc[4][4] = {};

    // buffer layout (ushort): buf*24576 + [A: h*8192 + rg*512 | B: 16384 + h*4096 + rg*512]
#define GLD(srcp, dstoff)                                                                  \
    __builtin_amdgcn_global_load_lds((const __attribute__((address_space(1))) void*)(srcp), \
                                     (__attribute__((address_space(3))) void*)(sm + (dstoff)), 16, 0, 0)
    // full-tile stage (prologue): 6 loads/thread
#define STAGE_ALL(buf, k0)                                                                 \
    {                                                                                      \
        GLD(A  + (size_t)(m0 + wid * 16 + srow) * 1024 + (k0) + scol,        (buf) * 24576 + wid * 512);              \
        GLD(A  + (size_t)(m0 + (wid + 8) * 16 + srow) * 1024 + (k0) + scol,  (buf) * 24576 + (wid + 8) * 512);        \
        GLD(A  + (size_t)(m0 + wid * 16 + srow) * 1024 + (k0) + 32 + scol,       (buf) * 24576 + 8192 + wid * 512);   \
        GLD(A  + (size_t)(m0 + (wid + 8) * 16 + srow) * 1024 + (k0) + 32 + scol, (buf) * 24576 + 8192 + (wid + 8) * 512); \
        GLD(Bt + (size_t)(n0 + wid * 16 + srow) * 1024 + (k0) + scol,        (buf) * 24576 + 16384 + wid * 512);      \
        GLD(Bt + (size_t)(n0 + wid * 16 + srow) * 1024 + (k0) + 32 + scol,   (buf) * 24576 + 16384 + 4096 + wid * 512); \
    }

    STAGE_ALL(0, 0);
    STAGE_ALL(1, 64);
    asm volatile("s_waitcnt vmcnt(6)" ::: "memory");  // tile 0 resident; tile 1 in flight
    __builtin_amdgcn_s_barrier();

    for (int t = 0; t < 16; ++t) {
        const int cur = t % 3;
        const int nb = (t + 2) % 3;
        const int k2 = (t + 2) * 64;
        const bool st = (t < 14);
        const ushort* base = sm + cur * 24576;
#pragma unroll
        for (int q = 0; q < 4; ++q) {
            const int i0 = (q >> 1) * 2;
            const int j0 = (q & 1) * 2;
            // ds-read this phase's fragments (conflict-free chunked layout)
            bf16x8 aF[2][2], bF[2][2];  // [d][kk]
#pragma unroll
            for (int d = 0; d < 2; ++d)
#pragma unroll
                for (int kk = 0; kk < 2; ++kk) {
                    aF[d][kk] = *(const bf16x8*)(base + kk * 8192 + (wm + (i0 + d) * 16 + fr) * 32 + fk);
                    bF[d][kk] = *(const bf16x8*)(base + 16384 + kk * 4096 + (wn + (j0 + d) * 16 + fr) * 32 + fk);
                }
            // stage slice for tile t+2 (2,2,1,1 over the 4 phases)
            if (st) {
                if (q == 0) {
                    GLD(A + (size_t)(m0 + wid * 16 + srow) * 1024 + k2 + scol,       nb * 24576 + wid * 512);
                    GLD(A + (size_t)(m0 + (wid + 8) * 16 + srow) * 1024 + k2 + scol, nb * 24576 + (wid + 8) * 512);
                } else if (q == 1) {
                    GLD(A + (size_t)(m0 + wid * 16 + srow) * 1024 + k2 + 32 + scol,       nb * 24576 + 8192 + wid * 512);
                    GLD(A + (size_t)(m0 + (wid + 8) * 16 + srow) * 1024 + k2 + 32 + scol, nb * 24576 + 8192 + (wid + 8) * 512);
                } else if (q == 2) {
                    GLD(Bt + (size_t)(n0 + wid * 16 + srow) * 1024 + k2 + scol, nb * 24576 + 16384 + wid * 512);
                } else {
                    GLD(Bt + (size_t)(n0 + wid * 16 + srow) * 1024 + k2 + 32 + scol, nb * 24576 + 16384 + 4096 + wid * 512);
                }
            }
            __builtin_amdgcn_s_barrier();
            asm volatile("s_waitcnt lgkmcnt(0)" ::: "memory");
            __builtin_amdgcn_s_setprio(1);
#pragma unroll
            for (int kk = 0; kk < 2; ++kk)
#pragma unroll
                for (int di = 0; di < 2; ++di)
#pragma unroll
                    for (int dj = 0; dj < 2; ++dj)
                        acc[i0 + di][j0 + dj] = __builtin_amdgcn_mfma_f32_16x16x32_bf16(
                            aF[di][kk], bF[dj][kk], acc[i0 + di][j0 + dj], 0, 0, 0);
            __builtin_amdgcn_s_setprio(0);
            if (q == 3) {
                if (t < 14) {
                    asm volatile("s_waitcnt vmcnt(6)" ::: "memory");  // tile t+1 resident
                } else if (t == 14) {
                    asm volatile("s_waitcnt vmcnt(0)" ::: "memory");  // tile 15 resident
                }
            }
            __builtin_amdgcn_s_barrier();
        }
    }
#undef STAGE_ALL
#undef GLD

    ushort* Cb = (n0 < 1024) ? P : Q;
    const int nc0 = n0 & 1023;
    const int cr = (lane >> 4) * 4;
    const int cc = lane & 15;
#pragma unroll
    for (int i = 0; i < 4; ++i)
#pragma unroll
        for (int j = 0; j < 4; ++j) {
            ushort* Cp = Cb + (size_t)(m0 + wm + i * 16 + cr) * 1024 + (nc0 + wn + j * 16 + cc);
#pragma unroll
            for (int r = 0; r < 4; ++r)
                Cp[(size_t)r * 1024] = f2bf(acc[i][j][r]);
        }
}

// ---- 3. span pass (identical to R20's k_span9) ----
__global__ __launch_bounds__(512, 2) void k_span9(const ushort* __restrict__ Pmat,
                                                  const ushort* __restrict__ Qmat,
                                                  const float* __restrict__ Rf,
                                                  const float* __restrict__ W2t,
                                                  const float* __restrict__ b2,
                                                  float* __restrict__ out, int nspans) {
    __shared__ float Rs[15 * 1024];
    const int tid = threadIdx.x;
    const int wid = tid >> 6, lane = tid & 63;
    const int b = blockIdx.x >> 6;
    const int s0 = (blockIdx.x & 63) << 3;

#pragma unroll
    for (int i = 0; i < 8; ++i) {
        int c = wid + (i << 3);
        if (c < 60) {
            int g = (c << 8) + lane * 4;
            __builtin_amdgcn_global_load_lds((const __attribute__((address_space(1))) void*)(Rf + g),
                                             (__attribute__((address_space(3))) void*)(Rs + g),
                                             16, 0, 0);
        }
    }

    f32x2 w2r2[3][2][4];
#pragma unroll
    for (int l = 0; l < 3; ++l)
#pragma unroll
        for (int it = 0; it < 2; ++it) {
            const float4* p = (const float4*)(W2t + l * 1024 + it * 512 + lane * 8);
            float4 v0 = p[0], v1 = p[1];
            w2r2[l][it][0] = (f32x2){v0.x, v0.y};
            w2r2[l][it][1] = (f32x2){v0.z, v0.w};
            w2r2[l][it][2] = (f32x2){v1.x, v1.y};
            w2r2[l][it][3] = (f32x2){v1.z, v1.w};
        }
    const float bb0 = b2[0], bb1 = b2[1], bb2 = b2[2];

    const int s = s0 + wid;
    f32x2 pf2[8];
    {
        const uint4* pr = (const uint4*)(Pmat + (((size_t)(b << 9) + s) << 10) + lane * 8);
        uint4 p0 = pr[0], p1 = pr[64];
        pf2[0] = up2(p0.x); pf2[1] = up2(p0.y); pf2[2] = up2(p0.z); pf2[3] = up2(p0.w);
        pf2[4] = up2(p1.x); pf2[5] = up2(p1.y); pf2[6] = up2(p1.z); pf2[7] = up2(p1.w);
    }

    __syncthreads();

    const int rrem = SEQ - s;
    const int nsp = (rrem < 15) ? rrem : 15;
    const int off = (rrem >= 15) ? 15 * s : (7575 - (rrem * (rrem + 1)) / 2);
    float* op = out + ((size_t)b * nspans + off) * 3;

    const uint4* qp = (const uint4*)(Qmat + (((size_t)(b << 9) + s) << 10) + lane * 8);

    int w = 0;
    for (; w + 1 < nsp; w += 2) {
        uint4 qa0 = qp[0],   qa1 = qp[64];
        uint4 qb0 = qp[128], qb1 = qp[192];
        qp += 256;
        f32x2 A0 = {0.f, 0.f}, A1 = {0.f, 0.f}, A2 = {0.f, 0.f};
        f32x2 B0 = {0.f, 0.f}, B1 = {0.f, 0.f}, B2 = {0.f, 0.f};
#pragma unroll
        for (int it = 0; it < 2; ++it) {
            uint4 qvA = it ? qa1 : qa0;
            uint4 qvB = it ? qb1 : qb0;
            const float4* rpA = (const float4*)(Rs + w * 1024 + it * 512 + lane * 8);
            const float4* rpB = (const float4*)(Rs + (w + 1) * 1024 + it * 512 + lane * 8);
            float4 raA = rpA[0], rbA = rpA[1];
            float4 raB = rpB[0], rbB = rpB[1];
            f32x2 q2A[4] = {up2(qvA.x), up2(qvA.y), up2(qvA.z), up2(qvA.w)};
            f32x2 q2B[4] = {up2(qvB.x), up2(qvB.y), up2(qvB.z), up2(qvB.w)};
            f32x2 r2A[4] = {(f32x2){raA.x, raA.y}, (f32x2){raA.z, raA.w},
                            (f32x2){rbA.x, rbA.y}, (f32x2){rbA.z, rbA.w}};
            f32x2 r2B[4] = {(f32x2){raB.x, raB.y}, (f32x2){raB.z, raB.w},
                            (f32x2){rbB.x, rbB.y}, (f32x2){rbB.z, rbB.w}};
#pragma unroll
            for (int k = 0; k < 4; ++k) {
                f32x2 hA = pf2[it * 4 + k] + q2A[k] + r2A[k];
                f32x2 hB = pf2[it * 4 + k] + q2B[k] + r2B[k];
                hA.x = fmaxf(hA.x, 0.f); hA.y = fmaxf(hA.y, 0.f);
                hB.x = fmaxf(hB.x, 0.f); hB.y = fmaxf(hB.y, 0.f);
                A0 += hA * w2r2[0][it][k];
                B0 += hB * w2r2[0][it][k];
                A1 += hA * w2r2[1][it][k];
                B1 += hB * w2r2[1][it][k];
                A2 += hA * w2r2[2][it][k];
                B2 += hB * w2r2[2][it][k];
            }
        }
        float a0 = A0.x + A0.y, b0 = B0.x + B0.y;
        float a1 = A1.x + A1.y, b1v = B1.x + B1.y;
        float a2 = A2.x + A2.y, b2v = B2.x + B2.y;
        a0 = wave_sum63(a0); b0 = wave_sum63(b0);
        a1 = wave_sum63(a1); b1v = wave_sum63(b1v);
        a2 = wave_sum63(a2); b2v = wave_sum63(b2v);
        if (lane == 63) {
            op[w * 3 + 0] = a0 + bb0;
            op[w * 3 + 1] = a1 + bb1;
            op[w * 3 + 2] = a2 + bb2;
            op[w * 3 + 3] = b0 + bb0;
            op[w * 3 + 4] = b1v + bb1;
            op[w * 3 + 5] = b2v + bb2;
        }
    }
    if (w < nsp) {
        uint4 qa0 = qp[0], qa1 = qp[64];
        f32x2 A0 = {0.f, 0.f}, A1 = {0.f, 0.f}, A2 = {0.f, 0.f};
#pragma unroll
        for (int it = 0; it < 2; ++it) {
            uint4 qv = it ? qa1 : qa0;
            const float4* rp = (const float4*)(Rs + w * 1024 + it * 512 + lane * 8);
            float4 ra = rp[0], rb = rp[1];
            f32x2 q2[4] = {up2(qv.x), up2(qv.y), up2(qv.z), up2(qv.w)};
            f32x2 r2[4] = {(f32x2){ra.x, ra.y}, (f32x2){ra.z, ra.w},
                           (f32x2){rb.x, rb.y}, (f32x2){rb.z, rb.w}};
#pragma unroll
            for (int k = 0; k < 4; ++k) {
                f32x2 h = pf2[it * 4 + k] + q2[k] + r2[k];
                h.x = fmaxf(h.x, 0.f); h.y = fmaxf(h.y, 0.f);
                A0 += h * w2r2[0][it][k];
                A1 += h * w2r2[1][it][k];
                A2 += h * w2r2[2][it][k];
            }
        }
        float a0 = A0.x + A0.y;
        float a1 = A1.x + A1.y;
        float a2 = A2.x + A2.y;
        a0 = wave_sum63(a0);
        a1 = wave_sum63(a1);
        a2 = wave_sum63(a2);
        if (lane == 63) {
            op[w * 3 + 0] = a0 + bb0;
            op[w * 3 + 1] = a1 + bb1;
            op[w * 3 + 2] = a2 + bb2;
        }
    }
}

extern "C" void kernel_launch(void* const* d_in, const int* in_sizes, int n_in,
                              void* d_out, int out_size, void* d_ws, size_t ws_size,
                              hipStream_t stream) {
    const float* seq    = (const float*)d_in[0];
    const float* wemb   = (const float*)d_in[1];
    const float* W1     = (const float*)d_in[2];
    const float* b1     = (const float*)d_in[3];
    const float* W2     = (const float*)d_in[4];
    const float* b2     = (const float*)d_in[5];
    float* out = (float*)d_out;
    int nspans = in_sizes[6];

    char* ws = (char*)d_ws;
    ushort* seqb = (ushort*)ws;                  // 8 MiB  (4096x1024 bf16)
    ushort* Bt   = (ushort*)(ws + (8u << 20));   // 4 MiB  (2048x1024 bf16)
    ushort* Pmat = (ushort*)(ws + (12u << 20));  // 8 MiB
    ushort* Qmat = (ushort*)(ws + (20u << 20));  // 8 MiB
    float*  Rf   = (float*)(ws + (28u << 20));   // 60 KiB (15x1024 f32)
    float*  W2t  = (float*)(ws + (29u << 20));   // 12 KiB (3x1024 f32)

    // allow 144 KB dynamic LDS for the 3-deep GEMM pipeline (host-side attr, not a stream op)
    hipFuncSetAttribute((const void*)k_gemm2,
                        hipFuncAttributeMaxDynamicSharedMemorySize, 147456);

    hipLaunchKernelGGL(k_prep, dim3(6144), dim3(256), 0, stream, seq, W1, seqb, Bt);
    hipLaunchKernelGGL(k_gemm2, dim3(292), dim3(512), 147456, stream,
                       seqb, Bt, wemb, W1, b1, W2, Pmat, Qmat, Rf, W2t);
    hipLaunchKernelGGL(k_span9, dim3(BATCH * 64), dim3(512), 0, stream,
                       Pmat, Qmat, Rf, W2t, b2, out, nspans);
}

// Round 22
// 53.107 us; speedup vs baseline: 1.1612x; 1.1612x over previous
//
#include <hip/hip_runtime.h>
#include <stdint.h>

#define SEQ 512
#define BATCH 8
#define HID 1024

typedef __attribute__((ext_vector_type(8))) __bf16 bf16x8;
typedef __attribute__((ext_vector_type(4))) float f32x4;
typedef __attribute__((ext_vector_type(2))) float f32x2;

__device__ __forceinline__ unsigned short f2bf(float f) {
    unsigned int u = __float_as_uint(f);
    unsigned int r = 0x7fffu + ((u >> 16) & 1u);
    return (unsigned short)((u + r) >> 16);
}

__device__ __forceinline__ f32x2 up2(unsigned int v) {
    f32x2 r;
    r.x = __uint_as_float(v << 16);
    r.y = __uint_as_float(v & 0xffff0000u);
    return r;
}

template <int CTRL>
__device__ __forceinline__ float dpp_add(float x) {
    int t = __builtin_amdgcn_update_dpp(0, __float_as_int(x), CTRL, 0xf, 0xf, true);
    return x + __int_as_float(t);
}
__device__ __forceinline__ float wave_sum63(float x) {
    x = dpp_add<0x111>(x);
    x = dpp_add<0x112>(x);
    x = dpp_add<0x114>(x);
    x = dpp_add<0x118>(x);
    x = dpp_add<0x142>(x);
    x = dpp_add<0x143>(x);
    return x;
}

// ---- 1. prep: cast + transpose only (pure BW work) ----
// [0,4096): cast seq->bf16 | [4096,6144): W1[:2048]^T -> Bt bf16
__global__ __launch_bounds__(256) void k_prep(const float* __restrict__ seq,
                                              const float* __restrict__ W1,
                                              ushort* __restrict__ seqb,
                                              ushort* __restrict__ Bt) {
    __shared__ float tile[32][33];
    const int bid = blockIdx.x;
    const int tid = threadIdx.x;
    if (bid < 4096) {
        int i = bid * 256 + tid;  // < 1048576 = n4
        float4 v = ((const float4*)seq)[i];
        ushort4 o;
        o.x = f2bf(v.x); o.y = f2bf(v.y); o.z = f2bf(v.z); o.w = f2bf(v.w);
        ((ushort4*)seqb)[i] = o;
    } else {
        int idx = bid - 4096;
        int nb = (idx & 63) * 32, kb = (idx >> 6) * 32;
        int tx = tid & 31, ty = tid >> 5;
        int n = nb + tx;
        int rb = (n < 1024) ? 0 : 1024;
        int nc = n - rb;
#pragma unroll
        for (int i = 0; i < 4; ++i) {
            int k = kb + ty + i * 8;
            tile[ty + i * 8][tx] = W1[(size_t)(rb + k) * 1024 + nc];
        }
        __syncthreads();
#pragma unroll
        for (int i = 0; i < 4; ++i) {
            int n2 = nb + ty + i * 8;
            Bt[(size_t)n2 * 1024 + kb + tx] = f2bf(tile[tx][ty + i * 8]);
        }
    }
}

// ---- 2. bf16 MFMA GEMM + side partitions (width table, W2t) on tail blocks ----
// blocks [0,512): GEMM | [512,572): width table f32 | [572,584): W2t
__global__ __launch_bounds__(256) void k_gemm(const ushort* __restrict__ A,
                                              const ushort* __restrict__ Bt,
                                              const float* __restrict__ wemb,
                                              const float* __restrict__ W1,
                                              const float* __restrict__ b1,
                                              const float* __restrict__ W2,
                                              ushort* __restrict__ P,
                                              ushort* __restrict__ Q,
                                              float* __restrict__ Rf,
                                              float* __restrict__ W2t) {
    __shared__ ushort Al[2][8192];
    __shared__ ushort Bl[2][8192];
    const int tid = threadIdx.x;
    const int bid = blockIdx.x;
    if (bid >= 512) {
        if (bid < 572) {
            // width table: Rf[w][j] = b1[j] + sum_c wemb[w][c]*W1[2048+c][j]
            int idx = (bid - 512) * 256 + tid;  // < 15360
            int w = idx >> 10, j = idx & 1023;
            float a0 = b1[j], a1 = 0.f, a2 = 0.f, a3 = 0.f;
#pragma unroll
            for (int c = 0; c < 64; c += 4) {
                a0 = fmaf(wemb[w * 64 + c + 0], W1[(size_t)(2048 + c + 0) * 1024 + j], a0);
                a1 = fmaf(wemb[w * 64 + c + 1], W1[(size_t)(2048 + c + 1) * 1024 + j], a1);
                a2 = fmaf(wemb[w * 64 + c + 2], W1[(size_t)(2048 + c + 2) * 1024 + j], a2);
                a3 = fmaf(wemb[w * 64 + c + 3], W1[(size_t)(2048 + c + 3) * 1024 + j], a3);
            }
            Rf[idx] = (a0 + a1) + (a2 + a3);
        } else {
            int idx = (bid - 572) * 256 + tid;  // < 3072
            int l = idx >> 10, j = idx & 1023;
            W2t[idx] = W2[j * 3 + l];
        }
        return;
    }
    const int wid = tid >> 6;
    const int lane = tid & 63;
    const int x = bid & 7, t8 = bid >> 3;
    const int m0 = (((x >> 1) << 3) + (t8 >> 3)) * 128;
    const int n0 = (((x & 1) << 3) + (t8 & 7)) * 128;
    const int wm = (wid >> 1) * 64;
    const int wn = (wid & 1) * 64;
    const int srow = lane >> 2;
    const int scol = (lane & 3) * 8;
    const int fr = lane & 15;
    const int fk = (lane >> 4) * 8;

    f32x4 acc[4][4] = {};

    const ushort* Abase = A  + (size_t)(m0 + srow) * 1024 + scol;
    const ushort* Bbase = Bt + (size_t)(n0 + srow) * 1024 + scol;

#define STAGE(buf, k0)                                                                     \
    {                                                                                      \
        _Pragma("unroll")                                                                  \
        for (int r = 0; r < 4; ++r) {                                                      \
            int c = wid + 4 * r;                                                           \
            int half = c >> 3;                                                             \
            int rows = (c & 7) * 16;                                                       \
            const ushort* sa = Abase + (size_t)rows * 1024 + (k0) + half * 32;             \
            const ushort* sb = Bbase + (size_t)rows * 1024 + (k0) + half * 32;             \
            int loff = half * 4096 + rows * 32;                                            \
            __builtin_amdgcn_global_load_lds((const __attribute__((address_space(1))) void*)sa, \
                                             (__attribute__((address_space(3))) void*)(&Al[buf][loff]), \
                                             16, 0, 0);                                    \
            __builtin_amdgcn_global_load_lds((const __attribute__((address_space(1))) void*)sb, \
                                             (__attribute__((address_space(3))) void*)(&Bl[buf][loff]), \
                                             16, 0, 0);                                    \
        }                                                                                  \
    }

#define COMPUTE(cur)                                                                       \
    {                                                                                      \
        _Pragma("unroll")                                                                  \
        for (int kk = 0; kk < 2; ++kk) {                                                   \
            bf16x8 af[4], bg[4];                                                           \
            _Pragma("unroll")                                                              \
            for (int i = 0; i < 4; ++i)                                                    \
                af[i] = *(const bf16x8*)(&Al[cur][kk * 4096 + (wm + i * 16 + fr) * 32 + fk]); \
            _Pragma("unroll")                                                              \
            for (int j = 0; j < 4; ++j)                                                    \
                bg[j] = *(const bf16x8*)(&Bl[cur][kk * 4096 + (wn + j * 16 + fr) * 32 + fk]); \
            __builtin_amdgcn_s_setprio(1);                                                 \
            _Pragma("unroll")                                                              \
            for (int i = 0; i < 4; ++i)                                                    \
                _Pragma("unroll")                                                          \
                for (int j = 0; j < 4; ++j)                                                \
                    acc[i][j] = __builtin_amdgcn_mfma_f32_16x16x32_bf16(af[i], bg[j], acc[i][j], 0, 0, 0); \
            __builtin_amdgcn_s_setprio(0);                                                 \
        }                                                                                  \
    }

    STAGE(0, 0);
    for (int t = 0; t < 15; ++t) {
        const int cur = t & 1;
        STAGE(cur ^ 1, (t + 1) * 64);
        asm volatile("s_waitcnt vmcnt(8)" ::: "memory");
        __builtin_amdgcn_s_barrier();
        COMPUTE(cur);
        __builtin_amdgcn_s_barrier();
    }
    asm volatile("s_waitcnt vmcnt(0)" ::: "memory");
    __builtin_amdgcn_s_barrier();
    COMPUTE(1);
#undef STAGE
#undef COMPUTE

    ushort* Cb = (n0 < 1024) ? P : Q;
    const int nc0 = n0 & 1023;
    const int cr = (lane >> 4) * 4;
    const int cc = lane & 15;
#pragma unroll
    for (int i = 0; i < 4; ++i)
#pragma unroll
        for (int j = 0; j < 4; ++j) {
            ushort* Cp = Cb + (size_t)(m0 + wm + i * 16 + cr) * 1024 + (nc0 + wn + j * 16 + cc);
#pragma unroll
            for (int r = 0; r < 4; ++r)
                Cp[(size_t)r * 1024] = f2bf(acc[i][j][r]);
        }
}

// ---- 3. span pass: pk-math + 2-span pairing, fits 128-VGPR cap (no spills) ----
__global__ __launch_bounds__(512, 2) void k_span9(const ushort* __restrict__ Pmat,
                                                  const ushort* __restrict__ Qmat,
                                                  const float* __restrict__ Rf,
                                                  const float* __restrict__ W2t,
                                                  const float* __restrict__ b2,
                                                  float* __restrict__ out, int nspans) {
    __shared__ float Rs[15 * 1024];  // 60 KB f32
    const int tid = threadIdx.x;
    const int wid = tid >> 6, lane = tid & 63;
    const int b = blockIdx.x >> 6;
    const int s0 = (blockIdx.x & 63) << 3;

#pragma unroll
    for (int i = 0; i < 8; ++i) {
        int c = wid + (i << 3);
        if (c < 60) {
            int g = (c << 8) + lane * 4;
            __builtin_amdgcn_global_load_lds((const __attribute__((address_space(1))) void*)(Rf + g),
                                             (__attribute__((address_space(3))) void*)(Rs + g),
                                             16, 0, 0);
        }
    }

    f32x2 w2r2[3][2][4];
#pragma unroll
    for (int l = 0; l < 3; ++l)
#pragma unroll
        for (int it = 0; it < 2; ++it) {
            const float4* p = (const float4*)(W2t + l * 1024 + it * 512 + lane * 8);
            float4 v0 = p[0], v1 = p[1];
            w2r2[l][it][0] = (f32x2){v0.x, v0.y};
            w2r2[l][it][1] = (f32x2){v0.z, v0.w};
            w2r2[l][it][2] = (f32x2){v1.x, v1.y};
            w2r2[l][it][3] = (f32x2){v1.z, v1.w};
        }
    const float bb0 = b2[0], bb1 = b2[1], bb2 = b2[2];

    const int s = s0 + wid;
    f32x2 pf2[8];
    {
        const uint4* pr = (const uint4*)(Pmat + (((size_t)(b << 9) + s) << 10) + lane * 8);
        uint4 p0 = pr[0], p1 = pr[64];
        pf2[0] = up2(p0.x); pf2[1] = up2(p0.y); pf2[2] = up2(p0.z); pf2[3] = up2(p0.w);
        pf2[4] = up2(p1.x); pf2[5] = up2(p1.y); pf2[6] = up2(p1.z); pf2[7] = up2(p1.w);
    }

    __syncthreads();

    const int rrem = SEQ - s;
    const int nsp = (rrem < 15) ? rrem : 15;
    const int off = (rrem >= 15) ? 15 * s : (7575 - (rrem * (rrem + 1)) / 2);
    float* op = out + ((size_t)b * nspans + off) * 3;

    const uint4* qp = (const uint4*)(Qmat + (((size_t)(b << 9) + s) << 10) + lane * 8);

    int w = 0;
    for (; w + 1 < nsp; w += 2) {
        uint4 qa0 = qp[0],   qa1 = qp[64];   // row w
        uint4 qb0 = qp[128], qb1 = qp[192];  // row w+1
        qp += 256;
        f32x2 A0 = {0.f, 0.f}, A1 = {0.f, 0.f}, A2 = {0.f, 0.f};
        f32x2 B0 = {0.f, 0.f}, B1 = {0.f, 0.f}, B2 = {0.f, 0.f};
#pragma unroll
        for (int it = 0; it < 2; ++it) {
            uint4 qvA = it ? qa1 : qa0;
            uint4 qvB = it ? qb1 : qb0;
            const float4* rpA = (const float4*)(Rs + w * 1024 + it * 512 + lane * 8);
            const float4* rpB = (const float4*)(Rs + (w + 1) * 1024 + it * 512 + lane * 8);
            float4 raA = rpA[0], rbA = rpA[1];
            float4 raB = rpB[0], rbB = rpB[1];
            f32x2 q2A[4] = {up2(qvA.x), up2(qvA.y), up2(qvA.z), up2(qvA.w)};
            f32x2 q2B[4] = {up2(qvB.x), up2(qvB.y), up2(qvB.z), up2(qvB.w)};
            f32x2 r2A[4] = {(f32x2){raA.x, raA.y}, (f32x2){raA.z, raA.w},
                            (f32x2){rbA.x, rbA.y}, (f32x2){rbA.z, rbA.w}};
            f32x2 r2B[4] = {(f32x2){raB.x, raB.y}, (f32x2){raB.z, raB.w},
                            (f32x2){rbB.x, rbB.y}, (f32x2){rbB.z, rbB.w}};
#pragma unroll
            for (int k = 0; k < 4; ++k) {
                f32x2 hA = pf2[it * 4 + k] + q2A[k] + r2A[k];
                f32x2 hB = pf2[it * 4 + k] + q2B[k] + r2B[k];
                hA.x = fmaxf(hA.x, 0.f); hA.y = fmaxf(hA.y, 0.f);
                hB.x = fmaxf(hB.x, 0.f); hB.y = fmaxf(hB.y, 0.f);
                A0 += hA * w2r2[0][it][k];
                B0 += hB * w2r2[0][it][k];
                A1 += hA * w2r2[1][it][k];
                B1 += hB * w2r2[1][it][k];
                A2 += hA * w2r2[2][it][k];
                B2 += hB * w2r2[2][it][k];
            }
        }
        float a0 = A0.x + A0.y, b0 = B0.x + B0.y;
        float a1 = A1.x + A1.y, b1v = B1.x + B1.y;
        float a2 = A2.x + A2.y, b2v = B2.x + B2.y;
        a0 = wave_sum63(a0); b0 = wave_sum63(b0);
        a1 = wave_sum63(a1); b1v = wave_sum63(b1v);
        a2 = wave_sum63(a2); b2v = wave_sum63(b2v);
        if (lane == 63) {
            op[w * 3 + 0] = a0 + bb0;
            op[w * 3 + 1] = a1 + bb1;
            op[w * 3 + 2] = a2 + bb2;
            op[w * 3 + 3] = b0 + bb0;
            op[w * 3 + 4] = b1v + bb1;
            op[w * 3 + 5] = b2v + bb2;
        }
    }
    if (w < nsp) {  // odd tail
        uint4 qa0 = qp[0], qa1 = qp[64];
        f32x2 A0 = {0.f, 0.f}, A1 = {0.f, 0.f}, A2 = {0.f, 0.f};
#pragma unroll
        for (int it = 0; it < 2; ++it) {
            uint4 qv = it ? qa1 : qa0;
            const float4* rp = (const float4*)(Rs + w * 1024 + it * 512 + lane * 8);
            float4 ra = rp[0], rb = rp[1];
            f32x2 q2[4] = {up2(qv.x), up2(qv.y), up2(qv.z), up2(qv.w)};
            f32x2 r2[4] = {(f32x2){ra.x, ra.y}, (f32x2){ra.z, ra.w},
                           (f32x2){rb.x, rb.y}, (f32x2){rb.z, rb.w}};
#pragma unroll
            for (int k = 0; k < 4; ++k) {
                f32x2 h = pf2[it * 4 + k] + q2[k] + r2[k];
                h.x = fmaxf(h.x, 0.f); h.y = fmaxf(h.y, 0.f);
                A0 += h * w2r2[0][it][k];
                A1 += h * w2r2[1][it][k];
                A2 += h * w2r2[2][it][k];
            }
        }
        float a0 = A0.x + A0.y;
        float a1 = A1.x + A1.y;
        float a2 = A2.x + A2.y;
        a0 = wave_sum63(a0);
        a1 = wave_sum63(a1);
        a2 = wave_sum63(a2);
        if (lane == 63) {
            op[w * 3 + 0] = a0 + bb0;
            op[w * 3 + 1] = a1 + bb1;
            op[w * 3 + 2] = a2 + bb2;
        }
    }
}

extern "C" void kernel_launch(void* const* d_in, const int* in_sizes, int n_in,
                              void* d_out, int out_size, void* d_ws, size_t ws_size,
                              hipStream_t stream) {
    const float* seq    = (const float*)d_in[0];
    const float* wemb   = (const float*)d_in[1];
    const float* W1     = (const float*)d_in[2];
    const float* b1     = (const float*)d_in[3];
    const float* W2     = (const float*)d_in[4];
    const float* b2     = (const float*)d_in[5];
    float* out = (float*)d_out;
    int nspans = in_sizes[6];

    char* ws = (char*)d_ws;
    ushort* seqb = (ushort*)ws;                  // 8 MiB  (4096x1024 bf16)
    ushort* Bt   = (ushort*)(ws + (8u << 20));   // 4 MiB  (2048x1024 bf16)
    ushort* Pmat = (ushort*)(ws + (12u << 20));  // 8 MiB
    ushort* Qmat = (ushort*)(ws + (20u << 20));  // 8 MiB
    float*  Rf   = (float*)(ws + (28u << 20));   // 60 KiB (15x1024 f32)
    float*  W2t  = (float*)(ws + (29u << 20));   // 12 KiB (3x1024 f32)

    hipLaunchKernelGGL(k_prep, dim3(6144), dim3(256), 0, stream, seq, W1, seqb, Bt);
    hipLaunchKernelGGL(k_gemm, dim3(584), dim3(256), 0, stream,
                       seqb, Bt, wemb, W1, b1, W2, Pmat, Qmat, Rf, W2t);
    hipLaunchKernelGGL(k_span9, dim3(BATCH * 64), dim3(512), 0, stream,
                       Pmat, Qmat, Rf, W2t, b2, out, nspans);
}